// Round 4
// baseline (3025.881 us; speedup 1.0000x reference)
//
#include <hip/hip_runtime.h>
#include <cstdint>
#include <cstddef>

// Problem constants
#define B_    16
#define N_    4096
#define S_    1024     // NPOINT
#define K_    32       // NSAMPLE
#define CNT_F 524288.0f   // B*S*K
#define EPS_  1e-5f

// Ball-query segmentation (R14): 8 index-range segments per query.
#define SEG_    8
#define SEGLEN_ (N_ / SEG_)   // 512

// Workspace layout (bytes). Total ~188 MB.
#define OFF_NXYZ 0u                    // [B][S][3] f32              196,608
#define OFF_IDX  196608u               // [B][S][K] i32            2,097,152
#define OFF_PTST 2293760u              // [B][N][68] f32 (xyz|pts|0) 17,825,792
#define OFF_PRE  20119552u             // [BS][32][64] f16          67,108,864
#define OFF_PRE2 87228416u             // [BS][32][64] f16          67,108,864
#define OFF_PART 154337280u            // [BS][256] f32             16,777,216
#define OFF_MM3  171114496u            // [BS][2][128] f32          16,777,216
#define OFF_ACC  187891712u            // [3][256] f32                   3,072
// bq segment scratch lives in the (not-yet-written) PRE region:
//   segidx [BS][SEG][K] i32 = 16,777,216 ; segcnt [BS][SEG] i32 = 524,288

// fma-chain dot4 for conv inner loops (continuous path, fma-safe).
__device__ __forceinline__ float dot4(float acc, float4 f, float4 wt) {
  return fmaf(f.w, wt.w, fmaf(f.z, wt.z, fmaf(f.y, wt.y, fmaf(f.x, wt.x, acc))));
}

// ---------------------------------------------------------------------------
// Transpose xyz[B,3,N] + points[B,64,N] -> ptsT[B,N,68] (col 67 = 0 pad)
// ---------------------------------------------------------------------------
__global__ __launch_bounds__(256) void transpose_kernel(
    const float* __restrict__ xyz, const float* __restrict__ pts,
    float* __restrict__ ptsT) {
  __shared__ float tile[64 * 69];
  int blk = blockIdx.x;
  int b = blk >> 6;
  int n0 = (blk & 63) << 6;
  int t = threadIdx.x;
  int wave = t >> 6, ln = t & 63;
  int n = n0 + ln;
  for (int cc = wave; cc < 68; cc += 4) {
    float v;
    if (cc < 3)       v = xyz[(size_t)(b * 3 + cc) * N_ + n];
    else if (cc < 67) v = pts[(size_t)(b * 64 + (cc - 3)) * N_ + n];
    else              v = 0.f;
    tile[ln * 69 + cc] = v;
  }
  __syncthreads();
  for (int f = t; f < 64 * 68; f += 256) {
    int r = f / 68, c = f - r * 68;
    ptsT[(size_t)(b * N_ + n0 + r) * 68 + c] = tile[r * 69 + c];
  }
}

// ---------------------------------------------------------------------------
// DPP argmax step carrying the winner 5-tuple (v, i, x, y, z). Proven exact
// in R14 (passed, absmax unchanged): the SINGLE condition
// (ov>bv)||(ov==bv&&oi<bi) gates all five selects -> selection bit-identical
// to the R8-proven (v,i) network; coords are bit-copies riding along.
// ---------------------------------------------------------------------------
template <int CTRL, int RM>
__device__ __forceinline__ void dpp_step5(float& bv, int& bi, float& bx,
                                          float& by, float& bz) {
  int ovi = __builtin_amdgcn_update_dpp(__float_as_int(bv), __float_as_int(bv),
                                        CTRL, RM, 0xf, false);
  int oi  = __builtin_amdgcn_update_dpp(bi, bi, CTRL, RM, 0xf, false);
  int oxi = __builtin_amdgcn_update_dpp(__float_as_int(bx), __float_as_int(bx),
                                        CTRL, RM, 0xf, false);
  int oyi = __builtin_amdgcn_update_dpp(__float_as_int(by), __float_as_int(by),
                                        CTRL, RM, 0xf, false);
  int ozi = __builtin_amdgcn_update_dpp(__float_as_int(bz), __float_as_int(bz),
                                        CTRL, RM, 0xf, false);
  float ov = __int_as_float(ovi);
  bool c = (ov > bv) || (ov == bv && oi < bi);
  if (c) {
    bv = ov; bi = oi;
    bx = __int_as_float(oxi); by = __int_as_float(oyi); bz = __int_as_float(ozi);
  }
}

// 15-cndmask mux: res = arr[jw] for jw in [0,16) without runtime indexing
// (runtime-indexed arrays go to scratch). Pure selects of bit-exact copies.
// Proven exact in R14.
#define MUX16(res, arr, s0, s1, s2, s3)                         \
  {                                                             \
    float u0 = (s0) ? arr[1] : arr[0];                          \
    float u1 = (s0) ? arr[3] : arr[2];                          \
    float u2 = (s0) ? arr[5] : arr[4];                          \
    float u3 = (s0) ? arr[7] : arr[6];                          \
    float u4 = (s0) ? arr[9] : arr[8];                          \
    float u5 = (s0) ? arr[11] : arr[10];                        \
    float u6 = (s0) ? arr[13] : arr[12];                        \
    float u7 = (s0) ? arr[15] : arr[14];                        \
    float v0 = (s1) ? u1 : u0;                                  \
    float v1 = (s1) ? u3 : u2;                                  \
    float v2 = (s1) ? u5 : u4;                                  \
    float v3 = (s1) ? u7 : u6;                                  \
    float w0 = (s2) ? v1 : v0;                                  \
    float w1 = (s2) ? v3 : v2;                                  \
    res = (s3) ? w1 : w0;                                       \
  }

// Per-batch FPS step: dist update + keep-left argmax tree + coord mux +
// 5-tuple DPP wave reduction. Macro (not function) so the register arrays
// stay in registers. Selection arithmetic identical to R1-proven code.
#define FPS_BODY(xr, yr, zr, dd, cx, cy, cz, BV, BI, BX, BY, BZ)      \
  {                                                                   \
    float tv[16]; int tj[16];                                         \
    _Pragma("unroll")                                                 \
    for (int j = 0; j < 16; ++j) {                                    \
      float dx = xr[j] - (cx), dy = yr[j] - (cy), dz = zr[j] - (cz);  \
      float d = dx * dx + dy * dy + dz * dz;  /* left-assoc, no fma */\
      float nd = fminf(dd[j], d);                                     \
      dd[j] = nd; tv[j] = nd; tj[j] = j;                              \
    }                                                                 \
    _Pragma("unroll")                                                 \
    for (int st = 1; st < 16; st <<= 1) {                             \
      _Pragma("unroll")                                               \
      for (int j0 = 0; j0 < 16; j0 += (st << 1)) {                    \
        if (tv[j0 + st] > tv[j0]) {                                   \
          tv[j0] = tv[j0 + st]; tj[j0] = tj[j0 + st];                 \
        }                                                             \
      }                                                               \
    }                                                                 \
    int jw = tj[0];                                                   \
    bool m0 = (jw & 1) != 0, m1 = (jw & 2) != 0,                      \
         m2 = (jw & 4) != 0, m3 = (jw & 8) != 0;                      \
    MUX16(BX, xr, m0, m1, m2, m3);                                    \
    MUX16(BY, yr, m0, m1, m2, m3);                                    \
    MUX16(BZ, zr, m0, m1, m2, m3);                                    \
    BV = tv[0];                                                       \
    BI = jw * 256 + t;                                                \
    dpp_step5<0x121, 0xf>(BV, BI, BX, BY, BZ); /* row_ror:1  */       \
    dpp_step5<0x122, 0xf>(BV, BI, BX, BY, BZ); /* row_ror:2  */       \
    dpp_step5<0x124, 0xf>(BV, BI, BX, BY, BZ); /* row_ror:4  */       \
    dpp_step5<0x128, 0xf>(BV, BI, BX, BY, BZ); /* row_ror:8  */       \
    dpp_step5<0x142, 0xa>(BV, BI, BX, BY, BZ); /* bcast15 -> 1,3 */   \
    dpp_step5<0x143, 0xc>(BV, BI, BX, BY, BZ); /* bcast31 -> 2,3 */   \
  }

// Cross-wave merge from slots (order 0->1->2->3, min index on tie) -> coords.
#define FPS_MERGE(SL, SI, CX, CY, CZ)                                  \
  {                                                                    \
    float4 c0 = SL[0], c1 = SL[1], c2 = SL[2], c3 = SL[3];             \
    int i0 = SI[0], i1 = SI[1], i2 = SI[2], i3 = SI[3];                \
    float mv = c0.x; int mi = i0;                                      \
    float mx = c0.y, my = c0.z, mz = c0.w;                             \
    if (c1.x > mv || (c1.x == mv && i1 < mi)) {                        \
      mv = c1.x; mi = i1; mx = c1.y; my = c1.z; mz = c1.w;             \
    }                                                                  \
    if (c2.x > mv || (c2.x == mv && i2 < mi)) {                        \
      mv = c2.x; mi = i2; mx = c2.y; my = c2.z; mz = c2.w;             \
    }                                                                  \
    if (c3.x > mv || (c3.x == mv && i3 < mi)) {                        \
      mv = c3.x; mi = i3; mx = c3.y; my = c3.z; mz = c3.w;             \
    }                                                                  \
    CX = mx; CY = my; CZ = mz;                                         \
  }

// ---------------------------------------------------------------------------
// FPS v9 (R15): DUAL-BATCH interleave. Each block owns TWO batches; each wave
// computes both batches' dist/tree/mux/DPP back-to-back, lane63 writes both
// slot tuples, ONE __syncthreads serves both, then both merges. The two
// independent chains let the scheduler hide the per-iteration LDS/barrier
// latency (~1300 cyc, measured R12-R14) under the other batch's VALU issue,
// and the barrier cost amortizes 2x. Coords ride in registers (R14-proven
// mux + dpp5 + float4 slots) -> no sx[far] LDS dependency, no big LDS arrays.
// Standard barrier (R14's spin handshake was pathological - reverted).
// Selection arithmetic UNCHANGED (proven exact R1-R14).
// __launch_bounds__(256,1): 1 wave/SIMD -> VGPR cap 512, no spill at ~190.
// ---------------------------------------------------------------------------
__global__ __launch_bounds__(256, 1) void fps_kernel(
    const float* __restrict__ xyz, float* __restrict__ nxyz,
    float* __restrict__ out0) {
#pragma clang fp contract(off)
  __shared__ float scent[2][S_ * 3];
  __shared__ __align__(16) float4 srv[2][2][4];   // [par][batch][wave]
  __shared__ int sri[2][2][4];
  int blk = blockIdx.x;        // 0..7
  int bA = blk * 2, bB = bA + 1;
  int t = threadIdx.x;         // 0..255
  int wv = t >> 6;             // wave id 0..3
  const float* xa = xyz + (size_t)bA * 3 * N_;
  const float* xc = xyz + (size_t)bB * 3 * N_;
  float xrA[16], yrA[16], zrA[16], dA[16];
  float xrB[16], yrB[16], zrB[16], dB[16];
#pragma unroll
  for (int j = 0; j < 16; ++j) {
    int i = j * 256 + t;                      // coalesced: lanes contiguous
    xrA[j] = xa[i]; yrA[j] = xa[N_ + i]; zrA[j] = xa[2 * N_ + i];
    xrB[j] = xc[i]; yrB[j] = xc[N_ + i]; zrB[j] = xc[2 * N_ + i];
    dA[j] = 1e10f; dB[j] = 1e10f;
  }
  // Centroid 0 = point 0 (same memory as the old sx[0] read -> bit-exact).
  float cxA = xa[0], cyA = xa[N_], czA = xa[2 * N_];
  float cxB = xc[0], cyB = xc[N_], czB = xc[2 * N_];
  __syncthreads();   // align waves at loop entry

  int par = 0;
  for (int s = 0; s < S_; ++s) {
    if (t == 0) {
      scent[0][s * 3]     = cxA;
      scent[0][s * 3 + 1] = cyA;
      scent[0][s * 3 + 2] = czA;
      scent[1][s * 3]     = cxB;
      scent[1][s * 3 + 1] = cyB;
      scent[1][s * 3 + 2] = czB;
    }
    float bvA, bxA, byA, bzA; int biA;
    float bvB, bxB, byB, bzB; int biB;
    FPS_BODY(xrA, yrA, zrA, dA, cxA, cyA, czA, bvA, biA, bxA, byA, bzA);
    FPS_BODY(xrB, yrB, zrB, dB, cxB, cyB, czB, bvB, biB, bxB, byB, bzB);
    if ((t & 63) == 63) {
      srv[par][0][wv] = make_float4(bvA, bxA, byA, bzA);
      sri[par][0][wv] = biA;
      srv[par][1][wv] = make_float4(bvB, bxB, byB, bzB);
      sri[par][1][wv] = biB;
    }
    __syncthreads();
    FPS_MERGE(srv[par][0], sri[par][0], cxA, cyA, czA);
    FPS_MERGE(srv[par][1], sri[par][1], cxB, cyB, czB);
    par ^= 1;  // double-buffered slots -> one barrier per iteration
  }
  __syncthreads();
  // Coalesced output writes from LDS staging, both batches.
  for (int f = t; f < 3 * S_; f += 256) {
    nxyz[(size_t)bA * 3 * S_ + f] = scent[0][f];        // [B][S][3]
    nxyz[(size_t)bB * 3 * S_ + f] = scent[1][f];
  }
  for (int q = t; q < S_; q += 256) {                   // [B][3][S]
    out0[(size_t)bA * 3 * S_ + q]          = scent[0][q * 3];
    out0[(size_t)bA * 3 * S_ + S_ + q]     = scent[0][q * 3 + 1];
    out0[(size_t)bA * 3 * S_ + 2 * S_ + q] = scent[0][q * 3 + 2];
    out0[(size_t)bB * 3 * S_ + q]          = scent[1][q * 3];
    out0[(size_t)bB * 3 * S_ + S_ + q]     = scent[1][q * 3 + 1];
    out0[(size_t)bB * 3 * S_ + 2 * S_ + q] = scent[1][q * 3 + 2];
  }
}

// ---------------------------------------------------------------------------
// Ball query v3 (R14): 8-way segmented scan. Per-point arithmetic IDENTICAL
// to the R6-proven fma ordering; each segment scans its index range in
// ascending order with early break at K_, so concatenating segments in order
// yields exactly "first K_ indices with d <= r^2".
// ---------------------------------------------------------------------------
__global__ __launch_bounds__(64) void bq_seg_kernel(
    const float* __restrict__ xyz, const float* __restrict__ nxyz,
    int* __restrict__ segidx, int* __restrict__ segcnt) {
#pragma clang fp contract(off)
  int q = blockIdx.x * 64 + threadIdx.x;
  int seg = blockIdx.y;
  int b = q >> 10;
  const float* xb = xyz + (size_t)b * 3 * N_;
  float cx = nxyz[(size_t)q * 3];
  float cy = nxyz[(size_t)q * 3 + 1];
  float cz = nxyz[(size_t)q * 3 + 2];
  float A = fmaf(cz, cz, fmaf(cy, cy, cx * cx));
  int* out = segidx + ((size_t)q * SEG_ + seg) * K_;
  int found = 0;
  int i0 = seg * SEGLEN_;
  for (int i = i0; i < i0 + SEGLEN_; ++i) {
    float x = xb[i], y = xb[N_ + i], z = xb[2 * N_ + i];
    float Bv  = fmaf(z, z, fmaf(y, y, x * x));
    float dot = fmaf(cz, z, fmaf(cy, y, cx * x));
    float d = fmaf(-2.0f, dot, A + Bv);
    if (d <= 0.04f) {
      out[found] = i;
      ++found;
      if (found >= K_) break;
    }
  }
  segcnt[q * SEG_ + seg] = found;
}

__global__ __launch_bounds__(64) void bq_merge_kernel(
    const int* __restrict__ segidx, const int* __restrict__ segcnt,
    int* __restrict__ idxb) {
  int q = blockIdx.x * 64 + threadIdx.x;
  int* out = idxb + (size_t)q * K_;
  int found = 0, first_i = -1;
#pragma unroll
  for (int s = 0; s < SEG_; ++s) {
    int c = segcnt[q * SEG_ + s];
    const int* src = segidx + ((size_t)q * SEG_ + s) * K_;
    for (int k = 0; k < c && found < K_; ++k) {
      int v = src[k];
      if (first_i < 0) first_i = v;
      out[found++] = v;
    }
  }
  for (int sfill = found; sfill < K_; ++sfill) out[sfill] = first_i;
}

// ---------------------------------------------------------------------------
// Layer 0 conv (tiled, validated): gather -> 32x67 @ 67x64 -> pre f16 +
// per-block channel sum/sumsq partials. 128 thr, 4x4 register tile.
// ---------------------------------------------------------------------------
__global__ __launch_bounds__(128) void convA_kernel(
    const float* __restrict__ ptsT, const float* __restrict__ nxyz,
    const int* __restrict__ idxb, const float* __restrict__ w0,
    const float* __restrict__ b0, _Float16* __restrict__ pre,
    float* __restrict__ part) {
  __shared__ __align__(16) float sfeat[32 * 72];
  __shared__ __align__(16) float sw[64 * 76];
  __shared__ float red0[64 * 8], red1[64 * 8];
  __shared__ __align__(16) _Float16 sstage[2048];
  __shared__ int sidx[32];
  int g = blockIdx.x;
  int t = threadIdx.x;
  int b = g >> 10;
  if (t < 32) sidx[t] = idxb[(size_t)g * K_ + t];
  for (int f = t; f < 64 * 68; f += 128) {
    int c = f / 68, ci = f - c * 68;
    sw[c * 76 + ci] = (ci < 67) ? w0[c * 67 + ci] : 0.f;
  }
  const float* nx = nxyz + (size_t)g * 3;
  float ctr0 = nx[0], ctr1 = nx[1], ctr2 = nx[2];
  __syncthreads();
  for (int f = t; f < 32 * 68; f += 128) {
    int k = f / 68, ci = f - k * 68;
    float v = ptsT[(size_t)(b * N_ + sidx[k]) * 68 + ci];  // col 67 is 0
    if (ci == 0) v -= ctr0; else if (ci == 1) v -= ctr1; else if (ci == 2) v -= ctr2;
    sfeat[k * 72 + ci] = v;
  }
  __syncthreads();
  int kq = t & 7, cq = t >> 3;
  float acc[4][4] = {};
  for (int ci = 0; ci < 68; ci += 4) {
    float4 fv[4], wv[4];
#pragma unroll
    for (int kk = 0; kk < 4; ++kk) fv[kk] = *(const float4*)&sfeat[(kq + 8 * kk) * 72 + ci];
#pragma unroll
    for (int cc = 0; cc < 4; ++cc) wv[cc] = *(const float4*)&sw[(cq + 16 * cc) * 76 + ci];
#pragma unroll
    for (int kk = 0; kk < 4; ++kk)
#pragma unroll
      for (int cc = 0; cc < 4; ++cc)
        acc[kk][cc] = dot4(acc[kk][cc], fv[kk], wv[cc]);
  }
#pragma unroll
  for (int cc = 0; cc < 4; ++cc) {
    int c = cq + 16 * cc;
    float bias = b0[c];
    float s1 = 0.f, s2 = 0.f;
#pragma unroll
    for (int kk = 0; kk < 4; ++kk) {
      float v = acc[kk][cc] + bias;
      sstage[(kq + 8 * kk) * 64 + c] = (_Float16)v;
      s1 += v; s2 += v * v;
    }
    red0[c * 8 + kq] = s1; red1[c * 8 + kq] = s2;
  }
  __syncthreads();
  if (t < 64) {
    float s1 = 0.f, s2 = 0.f;
#pragma unroll
    for (int qn = 0; qn < 8; ++qn) { s1 += red0[t * 8 + qn]; s2 += red1[t * 8 + qn]; }
    part[(size_t)g * 256 + t] = s1;
    part[(size_t)g * 256 + 64 + t] = s2;
  }
  uint4* dst = (uint4*)(pre + (size_t)g * 2048);
  const uint4* srcv = (const uint4*)sstage;
  dst[t] = srcv[t];
  dst[t + 128] = srcv[t + 128];
}

// ---------------------------------------------------------------------------
// Stats reduce (coalesced, R8-proven): thread t owns channel t; block sums 64
// consecutive rows; one atomicAdd per (block, channel). accum pre-zeroed.
// ---------------------------------------------------------------------------
__global__ __launch_bounds__(256) void red_kernel(
    const float* __restrict__ part, float* __restrict__ accum) {
  int t = threadIdx.x;
  size_t base = (size_t)blockIdx.x * 64 * 256 + t;
  float a = 0.f;
#pragma unroll 8
  for (int r = 0; r < 64; ++r) a += part[base + (size_t)r * 256];
  atomicAdd(accum + t, a);
}

// ---------------------------------------------------------------------------
// Layer 1 conv (tiled): BN0+relu on pre -> conv w1 -> pre2 + stats partials.
// ---------------------------------------------------------------------------
__global__ __launch_bounds__(128) void convB_kernel(
    const _Float16* __restrict__ pre, const float* __restrict__ accum,
    const float* __restrict__ gam, const float* __restrict__ bet,
    const float* __restrict__ w1, const float* __restrict__ b1,
    _Float16* __restrict__ pre2, float* __restrict__ part) {
  __shared__ __align__(16) float sfeat[32 * 72];
  __shared__ __align__(16) float sw[64 * 76];
  __shared__ float red0[64 * 8], red1[64 * 8];
  __shared__ __align__(16) _Float16 sstage[2048];
  __shared__ float ssc[64], ssh[64];
  int g = blockIdx.x;
  int t = threadIdx.x;
  if (t < 64) {
    float mu = accum[t] * (1.f / CNT_F);
    float var = accum[64 + t] * (1.f / CNT_F) - mu * mu;
    float sc = gam[t] / sqrtf(var + EPS_);
    ssc[t] = sc; ssh[t] = bet[t] - mu * sc;
  }
  for (int f = t; f < 64 * 64; f += 128) {
    int c = f >> 6, ci = f & 63;
    sw[c * 76 + ci] = w1[f];
  }
  __syncthreads();
  const _Float16* src = pre + (size_t)g * 2048;
  for (int f = t; f < 2048; f += 128) {
    int c = f & 63;
    float v = (float)src[f] * ssc[c] + ssh[c];
    sfeat[(f >> 6) * 72 + c] = fmaxf(v, 0.f);
  }
  __syncthreads();
  int kq = t & 7, cq = t >> 3;
  float acc[4][4] = {};
  for (int ci = 0; ci < 64; ci += 4) {
    float4 fv[4], wv[4];
#pragma unroll
    for (int kk = 0; kk < 4; ++kk) fv[kk] = *(const float4*)&sfeat[(kq + 8 * kk) * 72 + ci];
#pragma unroll
    for (int cc = 0; cc < 4; ++cc) wv[cc] = *(const float4*)&sw[(cq + 16 * cc) * 76 + ci];
#pragma unroll
    for (int kk = 0; kk < 4; ++kk)
#pragma unroll
      for (int cc = 0; cc < 4; ++cc)
        acc[kk][cc] = dot4(acc[kk][cc], fv[kk], wv[cc]);
  }
#pragma unroll
  for (int cc = 0; cc < 4; ++cc) {
    int c = cq + 16 * cc;
    float bias = b1[c];
    float s1 = 0.f, s2 = 0.f;
#pragma unroll
    for (int kk = 0; kk < 4; ++kk) {
      float v = acc[kk][cc] + bias;
      sstage[(kq + 8 * kk) * 64 + c] = (_Float16)v;
      s1 += v; s2 += v * v;
    }
    red0[c * 8 + kq] = s1; red1[c * 8 + kq] = s2;
  }
  __syncthreads();
  if (t < 64) {
    float s1 = 0.f, s2 = 0.f;
#pragma unroll
    for (int qn = 0; qn < 8; ++qn) { s1 += red0[t * 8 + qn]; s2 += red1[t * 8 + qn]; }
    part[(size_t)g * 256 + t] = s1;
    part[(size_t)g * 256 + 64 + t] = s2;
  }
  uint4* dst = (uint4*)(pre2 + (size_t)g * 2048);
  const uint4* srcv = (const uint4*)sstage;
  dst[t] = srcv[t];
  dst[t + 128] = srcv[t + 128];
}

// ---------------------------------------------------------------------------
// Layer 2 conv (tiled): BN1+relu on pre2 -> conv w2 (128 out) -> stats
// partials + per-group pre-BN max/min over k (relu∘BN monotone).
// ---------------------------------------------------------------------------
__global__ __launch_bounds__(256) void convC_kernel(
    const _Float16* __restrict__ pre2, const float* __restrict__ accum,
    const float* __restrict__ gam, const float* __restrict__ bet,
    const float* __restrict__ w2, const float* __restrict__ b2,
    float* __restrict__ mm, float* __restrict__ part) {
  __shared__ __align__(16) float sfeat[32 * 72];
  __shared__ __align__(16) float sw[128 * 76];
  __shared__ float red0[128 * 8], red1[128 * 8];
  __shared__ float rmax[128 * 8], rmin[128 * 8];
  __shared__ float ssc[64], ssh[64];
  int g = blockIdx.x;
  int t = threadIdx.x;
  if (t < 64) {
    float mu = accum[t] * (1.f / CNT_F);
    float var = accum[64 + t] * (1.f / CNT_F) - mu * mu;
    float sc = gam[t] / sqrtf(var + EPS_);
    ssc[t] = sc; ssh[t] = bet[t] - mu * sc;
  }
  for (int f = t; f < 128 * 64; f += 256) {
    int c = f >> 6, ci = f & 63;
    sw[c * 76 + ci] = w2[f];
  }
  __syncthreads();
  const _Float16* src = pre2 + (size_t)g * 2048;
  for (int f = t; f < 2048; f += 256) {
    int c = f & 63;
    float v = (float)src[f] * ssc[c] + ssh[c];
    sfeat[(f >> 6) * 72 + c] = fmaxf(v, 0.f);
  }
  __syncthreads();
  int kq = t & 7, cq = t >> 3;  // cq 0..31
  float acc[4][4] = {};
  for (int ci = 0; ci < 64; ci += 4) {
    float4 fv[4], wv[4];
#pragma unroll
    for (int kk = 0; kk < 4; ++kk) fv[kk] = *(const float4*)&sfeat[(kq + 8 * kk) * 72 + ci];
#pragma unroll
    for (int cc = 0; cc < 4; ++cc) wv[cc] = *(const float4*)&sw[(cq + 32 * cc) * 76 + ci];
#pragma unroll
    for (int kk = 0; kk < 4; ++kk)
#pragma unroll
      for (int cc = 0; cc < 4; ++cc)
        acc[kk][cc] = dot4(acc[kk][cc], fv[kk], wv[cc]);
  }
#pragma unroll
  for (int cc = 0; cc < 4; ++cc) {
    int c = cq + 32 * cc;
    float bias = b2[c];
    float s1 = 0.f, s2 = 0.f, mx = -3.4e38f, mn = 3.4e38f;
#pragma unroll
    for (int kk = 0; kk < 4; ++kk) {
      float v = acc[kk][cc] + bias;
      s1 += v; s2 += v * v;
      mx = fmaxf(mx, v); mn = fminf(mn, v);
    }
    red0[c * 8 + kq] = s1; red1[c * 8 + kq] = s2;
    rmax[c * 8 + kq] = mx; rmin[c * 8 + kq] = mn;
  }
  __syncthreads();
  if (t < 128) {
    float s1 = 0.f, s2 = 0.f, mx = -3.4e38f, mn = 3.4e38f;
#pragma unroll
    for (int qn = 0; qn < 8; ++qn) {
      s1 += red0[t * 8 + qn]; s2 += red1[t * 8 + qn];
      mx = fmaxf(mx, rmax[t * 8 + qn]); mn = fminf(mn, rmin[t * 8 + qn]);
    }
    part[(size_t)g * 256 + t] = s1;
    part[(size_t)g * 256 + 128 + t] = s2;
    mm[(size_t)g * 256 + t] = mx;
    mm[(size_t)g * 256 + 128 + t] = mn;
  }
}

// ---------------------------------------------------------------------------
// Final (coalesced, R8-proven): block = (b, 64-s tile); read mm rows, LDS
// transpose, write out[B,128,S] coalesced in s.
// ---------------------------------------------------------------------------
__global__ __launch_bounds__(256) void fin_kernel(
    const float* __restrict__ mm, const float* __restrict__ accum,
    const float* __restrict__ gam, const float* __restrict__ bet,
    float* __restrict__ out1) {
  __shared__ float tile[128 * 65];
  __shared__ float ssc[128], ssh[128];
  int blk = blockIdx.x;
  int b = blk >> 4;
  int s0 = (blk & 15) << 6;
  int t = threadIdx.x;
  if (t < 128) {
    float mu = accum[t] * (1.f / CNT_F);
    float var = accum[128 + t] * (1.f / CNT_F) - mu * mu;
    float sc = gam[t] / sqrtf(var + EPS_);
    ssc[t] = sc; ssh[t] = bet[t] - mu * sc;
  }
  __syncthreads();
  for (int f = t; f < 64 * 128; f += 256) {
    int sl = f >> 7, c = f & 127;
    const float* row = mm + (size_t)(b * S_ + s0 + sl) * 256;
    float sc = ssc[c];
    float v = (sc >= 0.f) ? row[c] : row[128 + c];
    tile[c * 65 + sl] = fmaxf(v * sc + ssh[c], 0.f);
  }
  __syncthreads();
  for (int f = t; f < 128 * 64; f += 256) {
    int c = f >> 6, sl = f & 63;
    out1[(size_t)b * 131072 + c * 1024 + s0 + sl] = tile[c * 65 + sl];
  }
}

// ---------------------------------------------------------------------------
extern "C" void kernel_launch(void* const* d_in, const int* in_sizes, int n_in,
                              void* d_out, int out_size, void* d_ws, size_t ws_size,
                              hipStream_t stream) {
  const float* xyz = (const float*)d_in[0];
  const float* pts = (const float*)d_in[1];
  const float* w0  = (const float*)d_in[2];
  const float* b0  = (const float*)d_in[3];
  const float* g0  = (const float*)d_in[4];
  const float* bt0 = (const float*)d_in[5];
  const float* w1  = (const float*)d_in[6];
  const float* b1  = (const float*)d_in[7];
  const float* g1  = (const float*)d_in[8];
  const float* bt1 = (const float*)d_in[9];
  const float* w2  = (const float*)d_in[10];
  const float* b2  = (const float*)d_in[11];
  const float* g2  = (const float*)d_in[12];
  const float* bt2 = (const float*)d_in[13];
  float* out = (float*)d_out;

  char* ws = (char*)d_ws;
  float*    nxyz  = (float*)(ws + OFF_NXYZ);
  int*      idxb  = (int*)(ws + OFF_IDX);
  float*    ptsT  = (float*)(ws + OFF_PTST);
  _Float16* pre   = (_Float16*)(ws + OFF_PRE);
  _Float16* pre2  = (_Float16*)(ws + OFF_PRE2);
  float*    part  = (float*)(ws + OFF_PART);
  float*    mm    = (float*)(ws + OFF_MM3);
  float*    accum = (float*)(ws + OFF_ACC);
  // bq segment scratch aliases the PRE region (free until convA writes it).
  int*      segidx = (int*)(ws + OFF_PRE);
  int*      segcnt = (int*)(ws + OFF_PRE + 16777216u);

  (void)hipMemsetAsync(accum, 0, 3 * 256 * sizeof(float), stream);

  fps_kernel<<<B_ / 2, 256, 0, stream>>>(xyz, nxyz, out);
  transpose_kernel<<<B_ * (N_ / 64), 256, 0, stream>>>(xyz, pts, ptsT);
  bq_seg_kernel<<<dim3((B_ * S_) / 64, SEG_), 64, 0, stream>>>(xyz, nxyz,
                                                               segidx, segcnt);
  bq_merge_kernel<<<(B_ * S_) / 64, 64, 0, stream>>>(segidx, segcnt, idxb);

  convA_kernel<<<B_ * S_, 128, 0, stream>>>(ptsT, nxyz, idxb, w0, b0, pre, part);
  red_kernel<<<256, 256, 0, stream>>>(part, accum);
  convB_kernel<<<B_ * S_, 128, 0, stream>>>(pre, accum, g0, bt0, w1, b1, pre2, part);
  red_kernel<<<256, 256, 0, stream>>>(part, accum + 256);
  convC_kernel<<<B_ * S_, 256, 0, stream>>>(pre2, accum + 256, g1, bt1, w2, b2, mm, part);
  red_kernel<<<256, 256, 0, stream>>>(part, accum + 512);
  fin_kernel<<<B_ * (S_ / 64), 256, 0, stream>>>(mm, accum + 512, g2, bt2,
                                                 out + B_ * 3 * S_);
}

// Round 5
// 1697.154 us; speedup vs baseline: 1.7829x; 1.7829x over previous
//
#include <hip/hip_runtime.h>
#include <cstdint>
#include <cstddef>

// Problem constants
#define B_    16
#define N_    4096
#define S_    1024     // NPOINT
#define K_    32       // NSAMPLE
#define CNT_F 524288.0f   // B*S*K
#define EPS_  1e-5f

// Ball-query segmentation (R14-proven): 8 index-range segments per query.
#define SEG_    8
#define SEGLEN_ (N_ / SEG_)   // 512

// Workspace layout (bytes). Total ~188 MB.
#define OFF_NXYZ 0u                    // [B][S][3] f32              196,608
#define OFF_IDX  196608u               // [B][S][K] i32            2,097,152
#define OFF_PTST 2293760u              // [B][N][68] f32 (xyz|pts|0) 17,825,792
#define OFF_PRE  20119552u             // [BS][32][64] f16          67,108,864
#define OFF_PRE2 87228416u             // [BS][32][64] f16          67,108,864
#define OFF_PART 154337280u            // [BS][256] f32             16,777,216
#define OFF_MM3  171114496u            // [BS][2][128] f32          16,777,216
#define OFF_ACC  187891712u            // [3][256] f32                   3,072
// bq segment scratch lives in the (not-yet-written) PRE region:
//   segidx [BS][SEG][K] i32 = 16,777,216 ; segcnt [BS][SEG] i32 = 524,288

typedef _Float16 half8 __attribute__((ext_vector_type(8)));

// fma-chain dot4 for conv inner loops (continuous path, fma-safe).
__device__ __forceinline__ float dot4(float acc, float4 f, float4 wt) {
  return fmaf(f.w, wt.w, fmaf(f.z, wt.z, fmaf(f.y, wt.y, fmaf(f.x, wt.x, acc))));
}

// ---------------------------------------------------------------------------
// DPP argmax step (proven R8): rotation network within 16-lane rows, then
// cross-row broadcasts; lane 63 ends with the full-wave (max, min-index).
// ---------------------------------------------------------------------------
template <int CTRL, int RM>
__device__ __forceinline__ void dpp_argmax_step(float& bv, int& bi) {
  int ovi = __builtin_amdgcn_update_dpp(__float_as_int(bv), __float_as_int(bv),
                                        CTRL, RM, 0xf, false);
  int oi  = __builtin_amdgcn_update_dpp(bi, bi, CTRL, RM, 0xf, false);
  float ov = __int_as_float(ovi);
  if (ov > bv || (ov == bv && oi < bi)) { bv = ov; bi = oi; }
}

// ---------------------------------------------------------------------------
// FPS (R12-proven form: 974 us, VGPR 88, NO spill) FUSED with the transpose:
// blocks 0..15 run FPS for batch b = blockIdx.x; blocks 16..1039 run the
// xyz/points -> ptsT[B,N,68] transpose on the otherwise-idle 240 CUs.
// Role branch is block-uniform (barriers legal). LDS aliased via one buffer.
// R4 post-mortem: R12's codegen is the only proven-fast fps; source kept
// semantically byte-identical (selection arithmetic exact, R1-R12).
// ---------------------------------------------------------------------------
__global__ __launch_bounds__(256) void fps_tr_kernel(
    const float* __restrict__ xyz, const float* __restrict__ pts,
    float* __restrict__ nxyz, float* __restrict__ out0,
    float* __restrict__ ptsT) {
#pragma clang fp contract(off)
  __shared__ __align__(16) char smem[61504];
  int t = threadIdx.x;

  if (blockIdx.x >= B_) {
    // ---------------- transpose role (R0-proven pattern) ----------------
    float* tile = (float*)smem;            // 64*69 floats = 17,664 B
    int blk = blockIdx.x - B_;
    int b = blk >> 6;
    int n0 = (blk & 63) << 6;
    int wave = t >> 6, ln = t & 63;
    int n = n0 + ln;
    for (int cc = wave; cc < 68; cc += 4) {
      float v;
      if (cc < 3)       v = xyz[(size_t)(b * 3 + cc) * N_ + n];
      else if (cc < 67) v = pts[(size_t)(b * 64 + (cc - 3)) * N_ + n];
      else              v = 0.f;
      tile[ln * 69 + cc] = v;
    }
    __syncthreads();
    for (int f = t; f < 64 * 68; f += 256) {
      int r = f / 68, c = f - r * 68;
      ptsT[(size_t)(b * N_ + n0 + r) * 68 + c] = tile[r * 69 + c];
    }
    return;
  }

  // ------------------------- FPS role (R12 verbatim) -------------------------
  float* sx    = (float*)smem;        // [4096]
  float* sy    = sx + N_;
  float* sz    = sy + N_;
  float* scent = sz + N_;             // [3072]
  float* redv  = scent + 3 * S_;      // [2][4] (offset 61440: 16B aligned)
  int*   redi  = (int*)(redv + 8);    // [2][4]

  int b = blockIdx.x;
  const float* xb = xyz + (size_t)b * 3 * N_;
  float xr[16], yr[16], zr[16], dist[16];
#pragma unroll
  for (int j = 0; j < 16; ++j) {
    int i = j * 256 + t;                      // coalesced: lanes contiguous
    float x = xb[i], y = xb[N_ + i], z = xb[2 * N_ + i];
    xr[j] = x; yr[j] = y; zr[j] = z;
    sx[i] = x; sy[i] = y; sz[i] = z;          // bank = t%32: conflict-free
    dist[j] = 1e10f;
  }
  __syncthreads();

  int far = 0, par = 0;
  for (int s = 0; s < S_; ++s) {
    float cx = sx[far], cy = sy[far], cz = sz[far];   // uniform broadcast read
    if (t == 0) {
      scent[s * 3]     = cx;
      scent[s * 3 + 1] = cy;
      scent[s * 3 + 2] = cz;
    }
    // Distance update: independent per j (no serial chain).
    float tv[16]; int tj[16];
#pragma unroll
    for (int j = 0; j < 16; ++j) {
      float dx = xr[j] - cx, dy = yr[j] - cy, dz = zr[j] - cz;
      float d = dx * dx + dy * dy + dz * dz;  // left-assoc, no fma
      float nd = fminf(dist[j], d);
      dist[j] = nd;
      tv[j] = nd; tj[j] = j;
    }
    // Depth-4 argmax tree; strict > keeps LEFT (lower j) on ties == serial
    // first-index-wins scan. All indices compile-time -> registers.
#pragma unroll
    for (int st = 1; st < 16; st <<= 1) {
#pragma unroll
      for (int j0 = 0; j0 < 16; j0 += (st << 1)) {
        if (tv[j0 + st] > tv[j0]) { tv[j0] = tv[j0 + st]; tj[j0] = tj[j0 + st]; }
      }
    }
    float bv = tv[0];
    int bi = tj[0] * 256 + t;
    // Wave argmax (VALU-only), winner in lane 63 of each wave.
    dpp_argmax_step<0x121, 0xf>(bv, bi);  // row_ror:1
    dpp_argmax_step<0x122, 0xf>(bv, bi);  // row_ror:2
    dpp_argmax_step<0x124, 0xf>(bv, bi);  // row_ror:4
    dpp_argmax_step<0x128, 0xf>(bv, bi);  // row_ror:8
    dpp_argmax_step<0x142, 0xa>(bv, bi);  // row_bcast15 -> rows 1,3
    dpp_argmax_step<0x143, 0xc>(bv, bi);  // row_bcast31 -> rows 2,3
    if ((t & 63) == 63) { redv[par * 4 + (t >> 6)] = bv; redi[par * 4 + (t >> 6)] = bi; }
    __syncthreads();
    float4 rv = *(const float4*)&redv[par * 4];
    int4   ri = *(const int4*)&redi[par * 4];
    bv = rv.x; bi = ri.x;
    if (rv.y > bv || (rv.y == bv && ri.y < bi)) { bv = rv.y; bi = ri.y; }
    if (rv.z > bv || (rv.z == bv && ri.z < bi)) { bv = rv.z; bi = ri.z; }
    if (rv.w > bv || (rv.w == bv && ri.w < bi)) { bv = rv.w; bi = ri.w; }
    far = bi;
    par ^= 1;  // double-buffered red slots -> one barrier per iteration
  }
  __syncthreads();
  // Coalesced output writes from LDS staging.
  for (int f = t; f < 3 * S_; f += 256)
    nxyz[(size_t)b * 3 * S_ + f] = scent[f];        // [B][S][3]
  for (int s = t; s < S_; s += 256) {               // [B][3][S]
    out0[(size_t)b * 3 * S_ + s]          = scent[s * 3];
    out0[(size_t)b * 3 * S_ + S_ + s]     = scent[s * 3 + 1];
    out0[(size_t)b * 3 * S_ + 2 * S_ + s] = scent[s * 3 + 2];
  }
}

// ---------------------------------------------------------------------------
// Ball query (R14-proven): 8-way segmented scan. Per-point arithmetic
// IDENTICAL to the R6-proven fma ordering; each segment scans ascending with
// early break at K_, so concatenating segments in order reproduces exactly
// "first K_ indices with d <= r^2".
// ---------------------------------------------------------------------------
__global__ __launch_bounds__(64) void bq_seg_kernel(
    const float* __restrict__ xyz, const float* __restrict__ nxyz,
    int* __restrict__ segidx, int* __restrict__ segcnt) {
#pragma clang fp contract(off)
  int q = blockIdx.x * 64 + threadIdx.x;
  int seg = blockIdx.y;
  int b = q >> 10;
  const float* xb = xyz + (size_t)b * 3 * N_;
  float cx = nxyz[(size_t)q * 3];
  float cy = nxyz[(size_t)q * 3 + 1];
  float cz = nxyz[(size_t)q * 3 + 2];
  float A = fmaf(cz, cz, fmaf(cy, cy, cx * cx));
  int* out = segidx + ((size_t)q * SEG_ + seg) * K_;
  int found = 0;
  int i0 = seg * SEGLEN_;
  for (int i = i0; i < i0 + SEGLEN_; ++i) {
    float x = xb[i], y = xb[N_ + i], z = xb[2 * N_ + i];
    float Bv  = fmaf(z, z, fmaf(y, y, x * x));
    float dot = fmaf(cz, z, fmaf(cy, y, cx * x));
    float d = fmaf(-2.0f, dot, A + Bv);
    if (d <= 0.04f) {
      out[found] = i;
      ++found;
      if (found >= K_) break;
    }
  }
  segcnt[q * SEG_ + seg] = found;
}

__global__ __launch_bounds__(64) void bq_merge_kernel(
    const int* __restrict__ segidx, const int* __restrict__ segcnt,
    int* __restrict__ idxb) {
  int q = blockIdx.x * 64 + threadIdx.x;
  int* out = idxb + (size_t)q * K_;
  int found = 0, first_i = -1;
#pragma unroll
  for (int s = 0; s < SEG_; ++s) {
    int c = segcnt[q * SEG_ + s];
    const int* src = segidx + ((size_t)q * SEG_ + s) * K_;
    for (int k = 0; k < c && found < K_; ++k) {
      int v = src[k];
      if (first_i < 0) first_i = v;
      out[found++] = v;
    }
  }
  for (int sfill = found; sfill < K_; ++sfill) out[sfill] = first_i;
}

// ---------------------------------------------------------------------------
// Layer 0 conv (tiled, validated): gather -> 32x67 @ 67x64 -> pre f16 +
// per-block channel sum/sumsq partials. 128 thr, 4x4 register tile.
// R16: gather vectorized as float4 (rows are 272B = 16B-aligned); centroid
// subtract confined to q==0 lanes .x/.y/.z — values bit-identical.
// ---------------------------------------------------------------------------
__global__ __launch_bounds__(128) void convA_kernel(
    const float* __restrict__ ptsT, const float* __restrict__ nxyz,
    const int* __restrict__ idxb, const float* __restrict__ w0,
    const float* __restrict__ b0, _Float16* __restrict__ pre,
    float* __restrict__ part) {
  __shared__ __align__(16) float sfeat[32 * 72];
  __shared__ __align__(16) float sw[64 * 76];
  __shared__ float red0[64 * 8], red1[64 * 8];
  __shared__ __align__(16) _Float16 sstage[2048];
  __shared__ int sidx[32];
  int g = blockIdx.x;
  int t = threadIdx.x;
  int b = g >> 10;
  if (t < 32) sidx[t] = idxb[(size_t)g * K_ + t];
  for (int f = t; f < 64 * 68; f += 128) {
    int c = f / 68, ci = f - c * 68;
    sw[c * 76 + ci] = (ci < 67) ? w0[c * 67 + ci] : 0.f;
  }
  const float* nx = nxyz + (size_t)g * 3;
  float ctr0 = nx[0], ctr1 = nx[1], ctr2 = nx[2];
  __syncthreads();
  for (int f = t; f < 32 * 17; f += 128) {   // 17 float4 per 68-col row
    int k = f / 17, q = f - k * 17;
    float4 v = *(const float4*)&ptsT[(size_t)(b * N_ + sidx[k]) * 68 + q * 4];
    if (q == 0) { v.x -= ctr0; v.y -= ctr1; v.z -= ctr2; }
    *(float4*)&sfeat[k * 72 + q * 4] = v;
  }
  __syncthreads();
  int kq = t & 7, cq = t >> 3;
  float acc[4][4] = {};
  for (int ci = 0; ci < 68; ci += 4) {
    float4 fv[4], wv[4];
#pragma unroll
    for (int kk = 0; kk < 4; ++kk) fv[kk] = *(const float4*)&sfeat[(kq + 8 * kk) * 72 + ci];
#pragma unroll
    for (int cc = 0; cc < 4; ++cc) wv[cc] = *(const float4*)&sw[(cq + 16 * cc) * 76 + ci];
#pragma unroll
    for (int kk = 0; kk < 4; ++kk)
#pragma unroll
      for (int cc = 0; cc < 4; ++cc)
        acc[kk][cc] = dot4(acc[kk][cc], fv[kk], wv[cc]);
  }
#pragma unroll
  for (int cc = 0; cc < 4; ++cc) {
    int c = cq + 16 * cc;
    float bias = b0[c];
    float s1 = 0.f, s2 = 0.f;
#pragma unroll
    for (int kk = 0; kk < 4; ++kk) {
      float v = acc[kk][cc] + bias;
      sstage[(kq + 8 * kk) * 64 + c] = (_Float16)v;
      s1 += v; s2 += v * v;
    }
    red0[c * 8 + kq] = s1; red1[c * 8 + kq] = s2;
  }
  __syncthreads();
  if (t < 64) {
    float s1 = 0.f, s2 = 0.f;
#pragma unroll
    for (int qn = 0; qn < 8; ++qn) { s1 += red0[t * 8 + qn]; s2 += red1[t * 8 + qn]; }
    part[(size_t)g * 256 + t] = s1;
    part[(size_t)g * 256 + 64 + t] = s2;
  }
  uint4* dst = (uint4*)(pre + (size_t)g * 2048);
  const uint4* srcv = (const uint4*)sstage;
  dst[t] = srcv[t];
  dst[t + 128] = srcv[t + 128];
}

// ---------------------------------------------------------------------------
// Stats reduce (coalesced, R8-proven): thread t owns channel t; block sums 64
// consecutive rows; one atomicAdd per (block, channel). accum pre-zeroed.
// ---------------------------------------------------------------------------
__global__ __launch_bounds__(256) void red_kernel(
    const float* __restrict__ part, float* __restrict__ accum) {
  int t = threadIdx.x;
  size_t base = (size_t)blockIdx.x * 64 * 256 + t;
  float a = 0.f;
#pragma unroll 8
  for (int r = 0; r < 64; ++r) a += part[base + (size_t)r * 256];
  atomicAdd(accum + t, a);
}

// ---------------------------------------------------------------------------
// Layer 1 conv (tiled): BN0+relu on pre -> conv w1 -> pre2 + stats partials.
// R16: activation read as half8 x2 (32B/thread, f16->f32 convert exact);
// w1 load as float4. Per-element arithmetic unchanged.
// ---------------------------------------------------------------------------
__global__ __launch_bounds__(128) void convB_kernel(
    const _Float16* __restrict__ pre, const float* __restrict__ accum,
    const float* __restrict__ gam, const float* __restrict__ bet,
    const float* __restrict__ w1, const float* __restrict__ b1,
    _Float16* __restrict__ pre2, float* __restrict__ part) {
  __shared__ __align__(16) float sfeat[32 * 72];
  __shared__ __align__(16) float sw[64 * 76];
  __shared__ float red0[64 * 8], red1[64 * 8];
  __shared__ __align__(16) _Float16 sstage[2048];
  __shared__ float ssc[64], ssh[64];
  int g = blockIdx.x;
  int t = threadIdx.x;
  if (t < 64) {
    float mu = accum[t] * (1.f / CNT_F);
    float var = accum[64 + t] * (1.f / CNT_F) - mu * mu;
    float sc = gam[t] / sqrtf(var + EPS_);
    ssc[t] = sc; ssh[t] = bet[t] - mu * sc;
  }
  for (int m = t; m < 1024; m += 128) {      // 4096 floats as float4
    int c = m >> 4, ci = (m & 15) * 4;
    *(float4*)&sw[c * 76 + ci] = *(const float4*)&w1[m * 4];
  }
  __syncthreads();
  {
    const half8* src8 = (const half8*)(pre + (size_t)g * 2048);
    int r = t >> 2, c0 = (t & 3) * 16;       // thread owns row r, cols c0..c0+15
    half8 h0 = src8[t * 2], h1 = src8[t * 2 + 1];
#pragma unroll
    for (int e = 0; e < 8; ++e) {
      float v = (float)h0[e] * ssc[c0 + e] + ssh[c0 + e];
      sfeat[r * 72 + c0 + e] = fmaxf(v, 0.f);
    }
#pragma unroll
    for (int e = 0; e < 8; ++e) {
      float v = (float)h1[e] * ssc[c0 + 8 + e] + ssh[c0 + 8 + e];
      sfeat[r * 72 + c0 + 8 + e] = fmaxf(v, 0.f);
    }
  }
  __syncthreads();
  int kq = t & 7, cq = t >> 3;
  float acc[4][4] = {};
  for (int ci = 0; ci < 64; ci += 4) {
    float4 fv[4], wv[4];
#pragma unroll
    for (int kk = 0; kk < 4; ++kk) fv[kk] = *(const float4*)&sfeat[(kq + 8 * kk) * 72 + ci];
#pragma unroll
    for (int cc = 0; cc < 4; ++cc) wv[cc] = *(const float4*)&sw[(cq + 16 * cc) * 76 + ci];
#pragma unroll
    for (int kk = 0; kk < 4; ++kk)
#pragma unroll
      for (int cc = 0; cc < 4; ++cc)
        acc[kk][cc] = dot4(acc[kk][cc], fv[kk], wv[cc]);
  }
#pragma unroll
  for (int cc = 0; cc < 4; ++cc) {
    int c = cq + 16 * cc;
    float bias = b1[c];
    float s1 = 0.f, s2 = 0.f;
#pragma unroll
    for (int kk = 0; kk < 4; ++kk) {
      float v = acc[kk][cc] + bias;
      sstage[(kq + 8 * kk) * 64 + c] = (_Float16)v;
      s1 += v; s2 += v * v;
    }
    red0[c * 8 + kq] = s1; red1[c * 8 + kq] = s2;
  }
  __syncthreads();
  if (t < 64) {
    float s1 = 0.f, s2 = 0.f;
#pragma unroll
    for (int qn = 0; qn < 8; ++qn) { s1 += red0[t * 8 + qn]; s2 += red1[t * 8 + qn]; }
    part[(size_t)g * 256 + t] = s1;
    part[(size_t)g * 256 + 64 + t] = s2;
  }
  uint4* dst = (uint4*)(pre2 + (size_t)g * 2048);
  const uint4* srcv = (const uint4*)sstage;
  dst[t] = srcv[t];
  dst[t + 128] = srcv[t + 128];
}

// ---------------------------------------------------------------------------
// Layer 2 conv (tiled): BN1+relu on pre2 -> conv w2 (128 out) -> stats
// partials + per-group pre-BN max/min over k (relu∘BN monotone).
// R16: activation read as half8 (16B/thread at 256 thr); w2 as float4.
// ---------------------------------------------------------------------------
__global__ __launch_bounds__(256) void convC_kernel(
    const _Float16* __restrict__ pre2, const float* __restrict__ accum,
    const float* __restrict__ gam, const float* __restrict__ bet,
    const float* __restrict__ w2, const float* __restrict__ b2,
    float* __restrict__ mm, float* __restrict__ part) {
  __shared__ __align__(16) float sfeat[32 * 72];
  __shared__ __align__(16) float sw[128 * 76];
  __shared__ float red0[128 * 8], red1[128 * 8];
  __shared__ float rmax[128 * 8], rmin[128 * 8];
  __shared__ float ssc[64], ssh[64];
  int g = blockIdx.x;
  int t = threadIdx.x;
  if (t < 64) {
    float mu = accum[t] * (1.f / CNT_F);
    float var = accum[64 + t] * (1.f / CNT_F) - mu * mu;
    float sc = gam[t] / sqrtf(var + EPS_);
    ssc[t] = sc; ssh[t] = bet[t] - mu * sc;
  }
  for (int m = t; m < 2048; m += 256) {      // 8192 floats as float4
    int c = m >> 4, ci = (m & 15) * 4;
    *(float4*)&sw[c * 76 + ci] = *(const float4*)&w2[m * 4];
  }
  __syncthreads();
  {
    const half8* src8 = (const half8*)(pre2 + (size_t)g * 2048);
    int r = t >> 3, c0 = (t & 7) * 8;        // thread owns row r, cols c0..c0+7
    half8 h0 = src8[t];
#pragma unroll
    for (int e = 0; e < 8; ++e) {
      float v = (float)h0[e] * ssc[c0 + e] + ssh[c0 + e];
      sfeat[r * 72 + c0 + e] = fmaxf(v, 0.f);
    }
  }
  __syncthreads();
  int kq = t & 7, cq = t >> 3;  // cq 0..31
  float acc[4][4] = {};
  for (int ci = 0; ci < 64; ci += 4) {
    float4 fv[4], wv[4];
#pragma unroll
    for (int kk = 0; kk < 4; ++kk) fv[kk] = *(const float4*)&sfeat[(kq + 8 * kk) * 72 + ci];
#pragma unroll
    for (int cc = 0; cc < 4; ++cc) wv[cc] = *(const float4*)&sw[(cq + 32 * cc) * 76 + ci];
#pragma unroll
    for (int kk = 0; kk < 4; ++kk)
#pragma unroll
      for (int cc = 0; cc < 4; ++cc)
        acc[kk][cc] = dot4(acc[kk][cc], fv[kk], wv[cc]);
  }
#pragma unroll
  for (int cc = 0; cc < 4; ++cc) {
    int c = cq + 32 * cc;
    float bias = b2[c];
    float s1 = 0.f, s2 = 0.f, mx = -3.4e38f, mn = 3.4e38f;
#pragma unroll
    for (int kk = 0; kk < 4; ++kk) {
      float v = acc[kk][cc] + bias;
      s1 += v; s2 += v * v;
      mx = fmaxf(mx, v); mn = fminf(mn, v);
    }
    red0[c * 8 + kq] = s1; red1[c * 8 + kq] = s2;
    rmax[c * 8 + kq] = mx; rmin[c * 8 + kq] = mn;
  }
  __syncthreads();
  if (t < 128) {
    float s1 = 0.f, s2 = 0.f, mx = -3.4e38f, mn = 3.4e38f;
#pragma unroll
    for (int qn = 0; qn < 8; ++qn) {
      s1 += red0[t * 8 + qn]; s2 += red1[t * 8 + qn];
      mx = fmaxf(mx, rmax[t * 8 + qn]); mn = fminf(mn, rmin[t * 8 + qn]);
    }
    part[(size_t)g * 256 + t] = s1;
    part[(size_t)g * 256 + 128 + t] = s2;
    mm[(size_t)g * 256 + t] = mx;
    mm[(size_t)g * 256 + 128 + t] = mn;
  }
}

// ---------------------------------------------------------------------------
// Final (coalesced, R8-proven): block = (b, 64-s tile); read mm rows, LDS
// transpose, write out[B,128,S] coalesced in s.
// ---------------------------------------------------------------------------
__global__ __launch_bounds__(256) void fin_kernel(
    const float* __restrict__ mm, const float* __restrict__ accum,
    const float* __restrict__ gam, const float* __restrict__ bet,
    float* __restrict__ out1) {
  __shared__ float tile[128 * 65];
  __shared__ float ssc[128], ssh[128];
  int blk = blockIdx.x;
  int b = blk >> 4;
  int s0 = (blk & 15) << 6;
  int t = threadIdx.x;
  if (t < 128) {
    float mu = accum[t] * (1.f / CNT_F);
    float var = accum[128 + t] * (1.f / CNT_F) - mu * mu;
    float sc = gam[t] / sqrtf(var + EPS_);
    ssc[t] = sc; ssh[t] = bet[t] - mu * sc;
  }
  __syncthreads();
  for (int f = t; f < 64 * 128; f += 256) {
    int sl = f >> 7, c = f & 127;
    const float* row = mm + (size_t)(b * S_ + s0 + sl) * 256;
    float sc = ssc[c];
    float v = (sc >= 0.f) ? row[c] : row[128 + c];
    tile[c * 65 + sl] = fmaxf(v * sc + ssh[c], 0.f);
  }
  __syncthreads();
  for (int f = t; f < 128 * 64; f += 256) {
    int c = f >> 6, sl = f & 63;
    out1[(size_t)b * 131072 + c * 1024 + s0 + sl] = tile[c * 65 + sl];
  }
}

// ---------------------------------------------------------------------------
extern "C" void kernel_launch(void* const* d_in, const int* in_sizes, int n_in,
                              void* d_out, int out_size, void* d_ws, size_t ws_size,
                              hipStream_t stream) {
  const float* xyz = (const float*)d_in[0];
  const float* pts = (const float*)d_in[1];
  const float* w0  = (const float*)d_in[2];
  const float* b0  = (const float*)d_in[3];
  const float* g0  = (const float*)d_in[4];
  const float* bt0 = (const float*)d_in[5];
  const float* w1  = (const float*)d_in[6];
  const float* b1  = (const float*)d_in[7];
  const float* g1  = (const float*)d_in[8];
  const float* bt1 = (const float*)d_in[9];
  const float* w2  = (const float*)d_in[10];
  const float* b2  = (const float*)d_in[11];
  const float* g2  = (const float*)d_in[12];
  const float* bt2 = (const float*)d_in[13];
  float* out = (float*)d_out;

  char* ws = (char*)d_ws;
  float*    nxyz  = (float*)(ws + OFF_NXYZ);
  int*      idxb  = (int*)(ws + OFF_IDX);
  float*    ptsT  = (float*)(ws + OFF_PTST);
  _Float16* pre   = (_Float16*)(ws + OFF_PRE);
  _Float16* pre2  = (_Float16*)(ws + OFF_PRE2);
  float*    part  = (float*)(ws + OFF_PART);
  float*    mm    = (float*)(ws + OFF_MM3);
  float*    accum = (float*)(ws + OFF_ACC);
  // bq segment scratch aliases the PRE region (free until convA writes it).
  int*      segidx = (int*)(ws + OFF_PRE);
  int*      segcnt = (int*)(ws + OFF_PRE + 16777216u);

  (void)hipMemsetAsync(accum, 0, 3 * 256 * sizeof(float), stream);

  // Fused: blocks 0..15 = FPS (16 CUs busy ~970us), blocks 16..1039 =
  // transpose riding on the otherwise-idle 240 CUs.
  fps_tr_kernel<<<B_ + B_ * (N_ / 64), 256, 0, stream>>>(xyz, pts, nxyz, out,
                                                         ptsT);
  bq_seg_kernel<<<dim3((B_ * S_) / 64, SEG_), 64, 0, stream>>>(xyz, nxyz,
                                                               segidx, segcnt);
  bq_merge_kernel<<<(B_ * S_) / 64, 64, 0, stream>>>(segidx, segcnt, idxb);

  convA_kernel<<<B_ * S_, 128, 0, stream>>>(ptsT, nxyz, idxb, w0, b0, pre, part);
  red_kernel<<<256, 256, 0, stream>>>(part, accum);
  convB_kernel<<<B_ * S_, 128, 0, stream>>>(pre, accum, g0, bt0, w1, b1, pre2, part);
  red_kernel<<<256, 256, 0, stream>>>(part, accum + 256);
  convC_kernel<<<B_ * S_, 256, 0, stream>>>(pre2, accum + 256, g1, bt1, w2, b2, mm, part);
  red_kernel<<<256, 256, 0, stream>>>(part, accum + 512);
  fin_kernel<<<B_ * (S_ / 64), 256, 0, stream>>>(mm, accum + 512, g2, bt2,
                                                 out + B_ * 3 * S_);
}

// Round 6
// 1348.432 us; speedup vs baseline: 2.2440x; 1.2586x over previous
//
#include <hip/hip_runtime.h>
#include <cstdint>
#include <cstddef>

// Problem constants
#define B_    16
#define N_    4096
#define S_    1024     // NPOINT
#define K_    32       // NSAMPLE
#define CNT_F 524288.0f   // B*S*K
#define EPS_  1e-5f

// Ball-query segmentation (R14-proven): 8 index-range segments per query.
#define SEG_    8
#define SEGLEN_ (N_ / SEG_)   // 512

// Workspace layout (bytes). Total ~188 MB.
#define OFF_NXYZ 0u                    // [B][S][3] f32              196,608
#define OFF_IDX  196608u               // [B][S][K] i32            2,097,152
#define OFF_PTST 2293760u              // [B][N][68] f32 (xyz|pts|0) 17,825,792
#define OFF_PRE  20119552u             // [BS][32][64] f16          67,108,864
#define OFF_PRE2 87228416u             // [BS][32][64] f16          67,108,864
#define OFF_PART 154337280u            // [BS][256] f32             16,777,216
#define OFF_MM3  171114496u            // [BS][2][128] f32          16,777,216
#define OFF_ACC  187891712u            // [3][256] f32                   3,072
// bq segment scratch lives in the (not-yet-written) PRE region:
//   segidx [BS][SEG][K] i32 = 16,777,216 ; segcnt [BS][SEG] i32 = 524,288

typedef _Float16 half8 __attribute__((ext_vector_type(8)));

// fma-chain dot4 for conv inner loops (continuous path, fma-safe).
__device__ __forceinline__ float dot4(float acc, float4 f, float4 wt) {
  return fmaf(f.w, wt.w, fmaf(f.z, wt.z, fmaf(f.y, wt.y, fmaf(f.x, wt.x, acc))));
}

// ---------------------------------------------------------------------------
// u64-key DPP max step (R17). Keys are positive-f64 bit patterns (sign 0,
// exponent <= 0x3FB: never NaN/Inf/zero), so v_max_f64 == lexicographic u64
// max == the R8-proven comparator (max value, tie -> min index). Same
// rotation network (ctrl/row_mask sequence) as the proven dpp_argmax_step.
// ---------------------------------------------------------------------------
template <int CTRL, int RM>
__device__ __forceinline__ uint64_t dpp_max64(uint64_t k) {
  int lo = __builtin_amdgcn_update_dpp((int)(uint32_t)k, (int)(uint32_t)k,
                                       CTRL, RM, 0xf, false);
  int hi = __builtin_amdgcn_update_dpp((int)(uint32_t)(k >> 32),
                                       (int)(uint32_t)(k >> 32),
                                       CTRL, RM, 0xf, false);
  uint64_t o = ((uint64_t)(uint32_t)hi << 32) | (uint32_t)lo;
  double m = fmax(__longlong_as_double((long long)k),
                  __longlong_as_double((long long)o));
  return (uint64_t)__double_as_longlong(m);
}

// ---------------------------------------------------------------------------
// FPS (R12-proven structure: 4 waves, 16 pts/lane, double-buffered slots, one
// barrier/iter) FUSED with the transpose (R5-proven: blocks >= 16 transpose
// on the otherwise-idle 240 CUs). R17 change: the argmax machinery uses
// monotone u64 keys, key = (bits(v) << 31) | (0x7FFFFFFF ^ idx):
//   - v >= 0 f32 -> bits(v) order-isomorphic to v; keys UNIQUE (idx distinct)
//   - max(key) == (max v, tie -> min idx) EXACTLY == proven comparator
//   - per-lane tree: 15 x v_max_f64 (was 15 x cmp+2 cndmask)
//   - DPP: 6 steps x (2 dpp + 1 max_f64) (was 6 x (2 dpp + cmp + 2 cndmask))
//   - cross-wave merge: 3 u64 compares; far = (~lo_word) & 0xFFF
// Distance arithmetic UNCHANGED (f32, contract(off), left-assoc, fminf).
// ---------------------------------------------------------------------------
__global__ __launch_bounds__(256) void fps_tr_kernel(
    const float* __restrict__ xyz, const float* __restrict__ pts,
    float* __restrict__ nxyz, float* __restrict__ out0,
    float* __restrict__ ptsT) {
#pragma clang fp contract(off)
  __shared__ __align__(16) char smem[61504];
  int t = threadIdx.x;

  if (blockIdx.x >= B_) {
    // ---------------- transpose role (R0-proven pattern) ----------------
    float* tile = (float*)smem;            // 64*69 floats = 17,664 B
    int blk = blockIdx.x - B_;
    int b = blk >> 6;
    int n0 = (blk & 63) << 6;
    int wave = t >> 6, ln = t & 63;
    int n = n0 + ln;
    for (int cc = wave; cc < 68; cc += 4) {
      float v;
      if (cc < 3)       v = xyz[(size_t)(b * 3 + cc) * N_ + n];
      else if (cc < 67) v = pts[(size_t)(b * 64 + (cc - 3)) * N_ + n];
      else              v = 0.f;
      tile[ln * 69 + cc] = v;
    }
    __syncthreads();
    for (int f = t; f < 64 * 68; f += 256) {
      int r = f / 68, c = f - r * 68;
      ptsT[(size_t)(b * N_ + n0 + r) * 68 + c] = tile[r * 69 + c];
    }
    return;
  }

  // ------------------------- FPS role -------------------------
  float*    sx    = (float*)smem;        // [4096]
  float*    sy    = sx + N_;
  float*    sz    = sy + N_;
  float*    scent = sz + N_;             // [3072]
  uint64_t* skey  = (uint64_t*)(scent + 3 * S_);  // [2][4] (off 61440, 16B ok)

  int b = blockIdx.x;
  const float* xb = xyz + (size_t)b * 3 * N_;
  float xr[16], yr[16], zr[16], dist[16];
  uint32_t Larr[16];
#pragma unroll
  for (int j = 0; j < 16; ++j) {
    int i = j * 256 + t;                      // coalesced: lanes contiguous
    float x = xb[i], y = xb[N_ + i], z = xb[2 * N_ + i];
    xr[j] = x; yr[j] = y; zr[j] = z;
    sx[i] = x; sy[i] = y; sz[i] = z;          // bank = t%32: conflict-free
    dist[j] = 1e10f;
    // j*256 and t occupy disjoint bits -> XOR == 0x7FFFFFFF ^ (j*256+t).
    Larr[j] = 0x7FFFFFFFu ^ (uint32_t)(j * 256 + t);
  }
  __syncthreads();

  int far = 0, par = 0;
  for (int s = 0; s < S_; ++s) {
    float cx = sx[far], cy = sy[far], cz = sz[far];   // uniform broadcast read
    if (t == 0) {
      scent[s * 3]     = cx;
      scent[s * 3 + 1] = cy;
      scent[s * 3 + 2] = cz;
    }
    // Distance update (arithmetic unchanged) + key build (3 instr per j).
    uint64_t ku[16];
#pragma unroll
    for (int j = 0; j < 16; ++j) {
      float dx = xr[j] - cx, dy = yr[j] - cy, dz = zr[j] - cz;
      float d = dx * dx + dy * dy + dz * dz;  // left-assoc, no fma
      float nd = fminf(dist[j], d);
      dist[j] = nd;
      ku[j] = ((uint64_t)__float_as_uint(nd) << 31) | Larr[j];
    }
    // Depth-4 max tree over unique keys == keep-left strict-> tree == serial
    // first-index-wins scan. Static indices -> registers.
#pragma unroll
    for (int st = 1; st < 16; st <<= 1) {
#pragma unroll
      for (int j0 = 0; j0 < 16; j0 += (st << 1)) {
        double a = __longlong_as_double((long long)ku[j0]);
        double c2 = __longlong_as_double((long long)ku[j0 + st]);
        ku[j0] = (uint64_t)__double_as_longlong(fmax(a, c2));
      }
    }
    uint64_t k = ku[0];
    // Wave max (VALU-only), winner key in lane 63 of each wave.
    k = dpp_max64<0x121, 0xf>(k);  // row_ror:1
    k = dpp_max64<0x122, 0xf>(k);  // row_ror:2
    k = dpp_max64<0x124, 0xf>(k);  // row_ror:4
    k = dpp_max64<0x128, 0xf>(k);  // row_ror:8
    k = dpp_max64<0x142, 0xa>(k);  // row_bcast15 -> rows 1,3
    k = dpp_max64<0x143, 0xc>(k);  // row_bcast31 -> rows 2,3
    if ((t & 63) == 63) skey[par * 4 + (t >> 6)] = k;
    __syncthreads();
    // Vectorized readback; u64 max over distinct keys (order-independent).
    ulonglong2 p0 = *(const ulonglong2*)&skey[par * 4];
    ulonglong2 p1 = *(const ulonglong2*)&skey[par * 4 + 2];
    uint64_t m = p0.x;
    if (p0.y > m) m = p0.y;
    if (p1.x > m) m = p1.x;
    if (p1.y > m) m = p1.y;
    far = (int)((~(uint32_t)m) & 0xFFFu);   // low 31 bits = 0x7FFFFFFF ^ idx
    par ^= 1;  // double-buffered slots -> one barrier per iteration
  }
  __syncthreads();
  // Coalesced output writes from LDS staging.
  for (int f = t; f < 3 * S_; f += 256)
    nxyz[(size_t)b * 3 * S_ + f] = scent[f];        // [B][S][3]
  for (int s = t; s < S_; s += 256) {               // [B][3][S]
    out0[(size_t)b * 3 * S_ + s]          = scent[s * 3];
    out0[(size_t)b * 3 * S_ + S_ + s]     = scent[s * 3 + 1];
    out0[(size_t)b * 3 * S_ + 2 * S_ + s] = scent[s * 3 + 2];
  }
}

// ---------------------------------------------------------------------------
// Ball query (R14-proven): 8-way segmented scan. Per-point arithmetic
// IDENTICAL to the R6-proven fma ordering; each segment scans ascending with
// early break at K_, so concatenating segments in order reproduces exactly
// "first K_ indices with d <= r^2".
// ---------------------------------------------------------------------------
__global__ __launch_bounds__(64) void bq_seg_kernel(
    const float* __restrict__ xyz, const float* __restrict__ nxyz,
    int* __restrict__ segidx, int* __restrict__ segcnt) {
#pragma clang fp contract(off)
  int q = blockIdx.x * 64 + threadIdx.x;
  int seg = blockIdx.y;
  int b = q >> 10;
  const float* xb = xyz + (size_t)b * 3 * N_;
  float cx = nxyz[(size_t)q * 3];
  float cy = nxyz[(size_t)q * 3 + 1];
  float cz = nxyz[(size_t)q * 3 + 2];
  float A = fmaf(cz, cz, fmaf(cy, cy, cx * cx));
  int* out = segidx + ((size_t)q * SEG_ + seg) * K_;
  int found = 0;
  int i0 = seg * SEGLEN_;
  for (int i = i0; i < i0 + SEGLEN_; ++i) {
    float x = xb[i], y = xb[N_ + i], z = xb[2 * N_ + i];
    float Bv  = fmaf(z, z, fmaf(y, y, x * x));
    float dot = fmaf(cz, z, fmaf(cy, y, cx * x));
    float d = fmaf(-2.0f, dot, A + Bv);
    if (d <= 0.04f) {
      out[found] = i;
      ++found;
      if (found >= K_) break;
    }
  }
  segcnt[q * SEG_ + seg] = found;
}

__global__ __launch_bounds__(64) void bq_merge_kernel(
    const int* __restrict__ segidx, const int* __restrict__ segcnt,
    int* __restrict__ idxb) {
  int q = blockIdx.x * 64 + threadIdx.x;
  int* out = idxb + (size_t)q * K_;
  int found = 0, first_i = -1;
#pragma unroll
  for (int s = 0; s < SEG_; ++s) {
    int c = segcnt[q * SEG_ + s];
    const int* src = segidx + ((size_t)q * SEG_ + s) * K_;
    for (int k = 0; k < c && found < K_; ++k) {
      int v = src[k];
      if (first_i < 0) first_i = v;
      out[found++] = v;
    }
  }
  for (int sfill = found; sfill < K_; ++sfill) out[sfill] = first_i;
}

// ---------------------------------------------------------------------------
// Layer 0 conv (tiled, validated): gather -> 32x67 @ 67x64 -> pre f16 +
// per-block channel sum/sumsq partials. 128 thr, 4x4 register tile.
// R16-proven: float4 gather (272B rows, 16B-aligned); centroid subtract
// confined to q==0 lanes x/y/z — values bit-identical.
// ---------------------------------------------------------------------------
__global__ __launch_bounds__(128) void convA_kernel(
    const float* __restrict__ ptsT, const float* __restrict__ nxyz,
    const int* __restrict__ idxb, const float* __restrict__ w0,
    const float* __restrict__ b0, _Float16* __restrict__ pre,
    float* __restrict__ part) {
  __shared__ __align__(16) float sfeat[32 * 72];
  __shared__ __align__(16) float sw[64 * 76];
  __shared__ float red0[64 * 8], red1[64 * 8];
  __shared__ __align__(16) _Float16 sstage[2048];
  __shared__ int sidx[32];
  int g = blockIdx.x;
  int t = threadIdx.x;
  int b = g >> 10;
  if (t < 32) sidx[t] = idxb[(size_t)g * K_ + t];
  for (int f = t; f < 64 * 68; f += 128) {
    int c = f / 68, ci = f - c * 68;
    sw[c * 76 + ci] = (ci < 67) ? w0[c * 67 + ci] : 0.f;
  }
  const float* nx = nxyz + (size_t)g * 3;
  float ctr0 = nx[0], ctr1 = nx[1], ctr2 = nx[2];
  __syncthreads();
  for (int f = t; f < 32 * 17; f += 128) {   // 17 float4 per 68-col row
    int k = f / 17, q = f - k * 17;
    float4 v = *(const float4*)&ptsT[(size_t)(b * N_ + sidx[k]) * 68 + q * 4];
    if (q == 0) { v.x -= ctr0; v.y -= ctr1; v.z -= ctr2; }
    *(float4*)&sfeat[k * 72 + q * 4] = v;
  }
  __syncthreads();
  int kq = t & 7, cq = t >> 3;
  float acc[4][4] = {};
  for (int ci = 0; ci < 68; ci += 4) {
    float4 fv[4], wv[4];
#pragma unroll
    for (int kk = 0; kk < 4; ++kk) fv[kk] = *(const float4*)&sfeat[(kq + 8 * kk) * 72 + ci];
#pragma unroll
    for (int cc = 0; cc < 4; ++cc) wv[cc] = *(const float4*)&sw[(cq + 16 * cc) * 76 + ci];
#pragma unroll
    for (int kk = 0; kk < 4; ++kk)
#pragma unroll
      for (int cc = 0; cc < 4; ++cc)
        acc[kk][cc] = dot4(acc[kk][cc], fv[kk], wv[cc]);
  }
#pragma unroll
  for (int cc = 0; cc < 4; ++cc) {
    int c = cq + 16 * cc;
    float bias = b0[c];
    float s1 = 0.f, s2 = 0.f;
#pragma unroll
    for (int kk = 0; kk < 4; ++kk) {
      float v = acc[kk][cc] + bias;
      sstage[(kq + 8 * kk) * 64 + c] = (_Float16)v;
      s1 += v; s2 += v * v;
    }
    red0[c * 8 + kq] = s1; red1[c * 8 + kq] = s2;
  }
  __syncthreads();
  if (t < 64) {
    float s1 = 0.f, s2 = 0.f;
#pragma unroll
    for (int qn = 0; qn < 8; ++qn) { s1 += red0[t * 8 + qn]; s2 += red1[t * 8 + qn]; }
    part[(size_t)g * 256 + t] = s1;
    part[(size_t)g * 256 + 64 + t] = s2;
  }
  uint4* dst = (uint4*)(pre + (size_t)g * 2048);
  const uint4* srcv = (const uint4*)sstage;
  dst[t] = srcv[t];
  dst[t + 128] = srcv[t + 128];
}

// ---------------------------------------------------------------------------
// Stats reduce (coalesced, R8-proven): thread t owns channel t; block sums 64
// consecutive rows; one atomicAdd per (block, channel). accum pre-zeroed.
// ---------------------------------------------------------------------------
__global__ __launch_bounds__(256) void red_kernel(
    const float* __restrict__ part, float* __restrict__ accum) {
  int t = threadIdx.x;
  size_t base = (size_t)blockIdx.x * 64 * 256 + t;
  float a = 0.f;
#pragma unroll 8
  for (int r = 0; r < 64; ++r) a += part[base + (size_t)r * 256];
  atomicAdd(accum + t, a);
}

// ---------------------------------------------------------------------------
// Layer 1 conv (tiled): BN0+relu on pre -> conv w1 -> pre2 + stats partials.
// R16-proven: half8 activation reads; float4 weight loads. Per-element
// arithmetic unchanged.
// ---------------------------------------------------------------------------
__global__ __launch_bounds__(128) void convB_kernel(
    const _Float16* __restrict__ pre, const float* __restrict__ accum,
    const float* __restrict__ gam, const float* __restrict__ bet,
    const float* __restrict__ w1, const float* __restrict__ b1,
    _Float16* __restrict__ pre2, float* __restrict__ part) {
  __shared__ __align__(16) float sfeat[32 * 72];
  __shared__ __align__(16) float sw[64 * 76];
  __shared__ float red0[64 * 8], red1[64 * 8];
  __shared__ __align__(16) _Float16 sstage[2048];
  __shared__ float ssc[64], ssh[64];
  int g = blockIdx.x;
  int t = threadIdx.x;
  if (t < 64) {
    float mu = accum[t] * (1.f / CNT_F);
    float var = accum[64 + t] * (1.f / CNT_F) - mu * mu;
    float sc = gam[t] / sqrtf(var + EPS_);
    ssc[t] = sc; ssh[t] = bet[t] - mu * sc;
  }
  for (int m = t; m < 1024; m += 128) {      // 4096 floats as float4
    int c = m >> 4, ci = (m & 15) * 4;
    *(float4*)&sw[c * 76 + ci] = *(const float4*)&w1[m * 4];
  }
  __syncthreads();
  {
    const half8* src8 = (const half8*)(pre + (size_t)g * 2048);
    int r = t >> 2, c0 = (t & 3) * 16;       // thread owns row r, cols c0..c0+15
    half8 h0 = src8[t * 2], h1 = src8[t * 2 + 1];
#pragma unroll
    for (int e = 0; e < 8; ++e) {
      float v = (float)h0[e] * ssc[c0 + e] + ssh[c0 + e];
      sfeat[r * 72 + c0 + e] = fmaxf(v, 0.f);
    }
#pragma unroll
    for (int e = 0; e < 8; ++e) {
      float v = (float)h1[e] * ssc[c0 + 8 + e] + ssh[c0 + 8 + e];
      sfeat[r * 72 + c0 + 8 + e] = fmaxf(v, 0.f);
    }
  }
  __syncthreads();
  int kq = t & 7, cq = t >> 3;
  float acc[4][4] = {};
  for (int ci = 0; ci < 64; ci += 4) {
    float4 fv[4], wv[4];
#pragma unroll
    for (int kk = 0; kk < 4; ++kk) fv[kk] = *(const float4*)&sfeat[(kq + 8 * kk) * 72 + ci];
#pragma unroll
    for (int cc = 0; cc < 4; ++cc) wv[cc] = *(const float4*)&sw[(cq + 16 * cc) * 76 + ci];
#pragma unroll
    for (int kk = 0; kk < 4; ++kk)
#pragma unroll
      for (int cc = 0; cc < 4; ++cc)
        acc[kk][cc] = dot4(acc[kk][cc], fv[kk], wv[cc]);
  }
#pragma unroll
  for (int cc = 0; cc < 4; ++cc) {
    int c = cq + 16 * cc;
    float bias = b1[c];
    float s1 = 0.f, s2 = 0.f;
#pragma unroll
    for (int kk = 0; kk < 4; ++kk) {
      float v = acc[kk][cc] + bias;
      sstage[(kq + 8 * kk) * 64 + c] = (_Float16)v;
      s1 += v; s2 += v * v;
    }
    red0[c * 8 + kq] = s1; red1[c * 8 + kq] = s2;
  }
  __syncthreads();
  if (t < 64) {
    float s1 = 0.f, s2 = 0.f;
#pragma unroll
    for (int qn = 0; qn < 8; ++qn) { s1 += red0[t * 8 + qn]; s2 += red1[t * 8 + qn]; }
    part[(size_t)g * 256 + t] = s1;
    part[(size_t)g * 256 + 64 + t] = s2;
  }
  uint4* dst = (uint4*)(pre2 + (size_t)g * 2048);
  const uint4* srcv = (const uint4*)sstage;
  dst[t] = srcv[t];
  dst[t + 128] = srcv[t + 128];
}

// ---------------------------------------------------------------------------
// Layer 2 conv (tiled): BN1+relu on pre2 -> conv w2 (128 out) -> stats
// partials + per-group pre-BN max/min over k (relu∘BN monotone).
// R16-proven: half8 activation reads; float4 weight loads.
// ---------------------------------------------------------------------------
__global__ __launch_bounds__(256) void convC_kernel(
    const _Float16* __restrict__ pre2, const float* __restrict__ accum,
    const float* __restrict__ gam, const float* __restrict__ bet,
    const float* __restrict__ w2, const float* __restrict__ b2,
    float* __restrict__ mm, float* __restrict__ part) {
  __shared__ __align__(16) float sfeat[32 * 72];
  __shared__ __align__(16) float sw[128 * 76];
  __shared__ float red0[128 * 8], red1[128 * 8];
  __shared__ float rmax[128 * 8], rmin[128 * 8];
  __shared__ float ssc[64], ssh[64];
  int g = blockIdx.x;
  int t = threadIdx.x;
  if (t < 64) {
    float mu = accum[t] * (1.f / CNT_F);
    float var = accum[64 + t] * (1.f / CNT_F) - mu * mu;
    float sc = gam[t] / sqrtf(var + EPS_);
    ssc[t] = sc; ssh[t] = bet[t] - mu * sc;
  }
  for (int m = t; m < 2048; m += 256) {      // 8192 floats as float4
    int c = m >> 4, ci = (m & 15) * 4;
    *(float4*)&sw[c * 76 + ci] = *(const float4*)&w2[m * 4];
  }
  __syncthreads();
  {
    const half8* src8 = (const half8*)(pre2 + (size_t)g * 2048);
    int r = t >> 3, c0 = (t & 7) * 8;        // thread owns row r, cols c0..c0+7
    half8 h0 = src8[t];
#pragma unroll
    for (int e = 0; e < 8; ++e) {
      float v = (float)h0[e] * ssc[c0 + e] + ssh[c0 + e];
      sfeat[r * 72 + c0 + e] = fmaxf(v, 0.f);
    }
  }
  __syncthreads();
  int kq = t & 7, cq = t >> 3;  // cq 0..31
  float acc[4][4] = {};
  for (int ci = 0; ci < 64; ci += 4) {
    float4 fv[4], wv[4];
#pragma unroll
    for (int kk = 0; kk < 4; ++kk) fv[kk] = *(const float4*)&sfeat[(kq + 8 * kk) * 72 + ci];
#pragma unroll
    for (int cc = 0; cc < 4; ++cc) wv[cc] = *(const float4*)&sw[(cq + 32 * cc) * 76 + ci];
#pragma unroll
    for (int kk = 0; kk < 4; ++kk)
#pragma unroll
      for (int cc = 0; cc < 4; ++cc)
        acc[kk][cc] = dot4(acc[kk][cc], fv[kk], wv[cc]);
  }
#pragma unroll
  for (int cc = 0; cc < 4; ++cc) {
    int c = cq + 32 * cc;
    float bias = b2[c];
    float s1 = 0.f, s2 = 0.f, mx = -3.4e38f, mn = 3.4e38f;
#pragma unroll
    for (int kk = 0; kk < 4; ++kk) {
      float v = acc[kk][cc] + bias;
      s1 += v; s2 += v * v;
      mx = fmaxf(mx, v); mn = fminf(mn, v);
    }
    red0[c * 8 + kq] = s1; red1[c * 8 + kq] = s2;
    rmax[c * 8 + kq] = mx; rmin[c * 8 + kq] = mn;
  }
  __syncthreads();
  if (t < 128) {
    float s1 = 0.f, s2 = 0.f, mx = -3.4e38f, mn = 3.4e38f;
#pragma unroll
    for (int qn = 0; qn < 8; ++qn) {
      s1 += red0[t * 8 + qn]; s2 += red1[t * 8 + qn];
      mx = fmaxf(mx, rmax[t * 8 + qn]); mn = fminf(mn, rmin[t * 8 + qn]);
    }
    part[(size_t)g * 256 + t] = s1;
    part[(size_t)g * 256 + 128 + t] = s2;
    mm[(size_t)g * 256 + t] = mx;
    mm[(size_t)g * 256 + 128 + t] = mn;
  }
}

// ---------------------------------------------------------------------------
// Final (coalesced, R8-proven): block = (b, 64-s tile); read mm rows, LDS
// transpose, write out[B,128,S] coalesced in s.
// ---------------------------------------------------------------------------
__global__ __launch_bounds__(256) void fin_kernel(
    const float* __restrict__ mm, const float* __restrict__ accum,
    const float* __restrict__ gam, const float* __restrict__ bet,
    float* __restrict__ out1) {
  __shared__ float tile[128 * 65];
  __shared__ float ssc[128], ssh[128];
  int blk = blockIdx.x;
  int b = blk >> 4;
  int s0 = (blk & 15) << 6;
  int t = threadIdx.x;
  if (t < 128) {
    float mu = accum[t] * (1.f / CNT_F);
    float var = accum[128 + t] * (1.f / CNT_F) - mu * mu;
    float sc = gam[t] / sqrtf(var + EPS_);
    ssc[t] = sc; ssh[t] = bet[t] - mu * sc;
  }
  __syncthreads();
  for (int f = t; f < 64 * 128; f += 256) {
    int sl = f >> 7, c = f & 127;
    const float* row = mm + (size_t)(b * S_ + s0 + sl) * 256;
    float sc = ssc[c];
    float v = (sc >= 0.f) ? row[c] : row[128 + c];
    tile[c * 65 + sl] = fmaxf(v * sc + ssh[c], 0.f);
  }
  __syncthreads();
  for (int f = t; f < 128 * 64; f += 256) {
    int c = f >> 6, sl = f & 63;
    out1[(size_t)b * 131072 + c * 1024 + s0 + sl] = tile[c * 65 + sl];
  }
}

// ---------------------------------------------------------------------------
extern "C" void kernel_launch(void* const* d_in, const int* in_sizes, int n_in,
                              void* d_out, int out_size, void* d_ws, size_t ws_size,
                              hipStream_t stream) {
  const float* xyz = (const float*)d_in[0];
  const float* pts = (const float*)d_in[1];
  const float* w0  = (const float*)d_in[2];
  const float* b0  = (const float*)d_in[3];
  const float* g0  = (const float*)d_in[4];
  const float* bt0 = (const float*)d_in[5];
  const float* w1  = (const float*)d_in[6];
  const float* b1  = (const float*)d_in[7];
  const float* g1  = (const float*)d_in[8];
  const float* bt1 = (const float*)d_in[9];
  const float* w2  = (const float*)d_in[10];
  const float* b2  = (const float*)d_in[11];
  const float* g2  = (const float*)d_in[12];
  const float* bt2 = (const float*)d_in[13];
  float* out = (float*)d_out;

  char* ws = (char*)d_ws;
  float*    nxyz  = (float*)(ws + OFF_NXYZ);
  int*      idxb  = (int*)(ws + OFF_IDX);
  float*    ptsT  = (float*)(ws + OFF_PTST);
  _Float16* pre   = (_Float16*)(ws + OFF_PRE);
  _Float16* pre2  = (_Float16*)(ws + OFF_PRE2);
  float*    part  = (float*)(ws + OFF_PART);
  float*    mm    = (float*)(ws + OFF_MM3);
  float*    accum = (float*)(ws + OFF_ACC);
  // bq segment scratch aliases the PRE region (free until convA writes it).
  int*      segidx = (int*)(ws + OFF_PRE);
  int*      segcnt = (int*)(ws + OFF_PRE + 16777216u);

  (void)hipMemsetAsync(accum, 0, 3 * 256 * sizeof(float), stream);

  // Fused: blocks 0..15 = FPS (16 CUs busy), blocks 16..1039 = transpose
  // riding on the otherwise-idle 240 CUs.
  fps_tr_kernel<<<B_ + B_ * (N_ / 64), 256, 0, stream>>>(xyz, pts, nxyz, out,
                                                         ptsT);
  bq_seg_kernel<<<dim3((B_ * S_) / 64, SEG_), 64, 0, stream>>>(xyz, nxyz,
                                                               segidx, segcnt);
  bq_merge_kernel<<<(B_ * S_) / 64, 64, 0, stream>>>(segidx, segcnt, idxb);

  convA_kernel<<<B_ * S_, 128, 0, stream>>>(ptsT, nxyz, idxb, w0, b0, pre, part);
  red_kernel<<<256, 256, 0, stream>>>(part, accum);
  convB_kernel<<<B_ * S_, 128, 0, stream>>>(pre, accum, g0, bt0, w1, b1, pre2, part);
  red_kernel<<<256, 256, 0, stream>>>(part, accum + 256);
  convC_kernel<<<B_ * S_, 256, 0, stream>>>(pre2, accum + 256, g1, bt1, w2, b2, mm, part);
  red_kernel<<<256, 256, 0, stream>>>(part, accum + 512);
  fin_kernel<<<B_ * (S_ / 64), 256, 0, stream>>>(mm, accum + 512, g2, bt2,
                                                 out + B_ * 3 * S_);
}